// Round 3
// baseline (806.183 us; speedup 1.0000x reference)
//
#include <hip/hip_runtime.h>
#include <cstdint>

#define B_ 4096
#define F_ 1024
#define H_ 16384
#define TOPK 64
#define MAXC 192
#define NBINS 2048
#define BINW 0.00390625f
// 2E: twice the bound on |a_fp16_stored - a_ref|.
// fp16-GEMM error <= 0.0031 (bf16's proven 0.025 scaled by 2^-3) +
// fp16 storage rounding <= 0.002  => E=0.010 gives ~2x headroom.
#define TWOE 0.020f

typedef unsigned short u16;
typedef __attribute__((ext_vector_type(8))) _Float16 f16x8;
typedef __attribute__((ext_vector_type(8))) unsigned short u16x8;
typedef __attribute__((ext_vector_type(4))) float f32x4;

__device__ __forceinline__ u16 f2bf(float f) {
  union { float f; uint32_t u; } v; v.f = f;
  uint32_t u = v.u;
  uint32_t r = u + 0x7FFFu + ((u >> 16) & 1u);
  return (u16)(r >> 16);
}
__device__ __forceinline__ float bf2f(u16 h) {
  union { uint32_t u; float f; } v; v.u = ((uint32_t)h) << 16; return v.f;
}
__device__ __forceinline__ u16 f2h(float f) {
  union { _Float16 h; u16 u; } v; v.h = (_Float16)f; return v.u;
}
__device__ __forceinline__ float h2f(u16 h) {
  union { _Float16 h; u16 u; } v; v.u = h; return (float)v.h;
}

__device__ __forceinline__ void async16(const void* g, void* l) {
  __builtin_amdgcn_global_load_lds(
      reinterpret_cast<const __attribute__((address_space(1))) uint32_t*>(
          reinterpret_cast<uintptr_t>(g)),
      reinterpret_cast<__attribute__((address_space(3))) uint32_t*>(
          reinterpret_cast<uintptr_t>(l)),
      16, 0, 0);
}

// ---- K0a: xbar = fp16(x - b_dec) ----
__global__ __launch_bounds__(256) void k_xbar(const float* __restrict__ x,
                                              const float* __restrict__ b_dec,
                                              u16* __restrict__ xbar) {
  int i = blockIdx.x * 256 + threadIdx.x;
  int base = i * 4;
  int col = base & (F_ - 1);
  float4 xv = *(const float4*)(x + base);
  float4 bv = *(const float4*)(b_dec + col);
  ushort4 o;
  o.x = f2h(xv.x - bv.x); o.y = f2h(xv.y - bv.y);
  o.z = f2h(xv.z - bv.z); o.w = f2h(xv.w - bv.w);
  *(ushort4*)(xbar + base) = o;
}

// ---- K0b: fp16 cast of W_enc ----
__global__ __launch_bounds__(256) void k_cast(const float* __restrict__ src,
                                              u16* __restrict__ dst) {
  size_t base = (size_t)(blockIdx.x * 256 + threadIdx.x) * 4;
  float4 v = *(const float4*)(src + base);
  ushort4 o; o.x = f2h(v.x); o.y = f2h(v.y); o.z = f2h(v.z); o.w = f2h(v.w);
  *(ushort4*)(dst + base) = o;
}

// ---- K0c: W_dec [F,H] fp32 -> W_decT [H,F] bf16 (decode path unchanged) ----
__global__ __launch_bounds__(256) void k_transpose(const float* __restrict__ Wdec,
                                                   u16* __restrict__ WdecT) {
  __shared__ float tile[32][33];
  int hb = blockIdx.x * 32, fb = blockIdx.y * 32;
  int tx = threadIdx.x & 31, ty = threadIdx.x >> 5;  // ty 0..7
#pragma unroll
  for (int i = 0; i < 32; i += 8)
    tile[ty + i][tx] = Wdec[(size_t)(fb + ty + i) * H_ + hb + tx];
  __syncthreads();
#pragma unroll
  for (int i = 0; i < 32; i += 8)
    WdecT[(size_t)(hb + ty + i) * F_ + fb + tx] = f2bf(tile[tx][ty + i]);
}

// ---- K1: fp16 MFMA GEMM, ring-3 counted-vmcnt pipeline, XCD column-stripe.
// Changes vs prior round (which drained vmcnt(0) at every __syncthreads):
//  * triple-buffered K-tiles; raw s_barrier + "s_waitcnt vmcnt(4)" keeps the
//    next tile's 4 global_load_lds in flight across the barrier (T4).
//  * 1-D grid remapped so each XCD owns a 16-wide bx stripe (B-panels = 4 MB,
//    exactly one XCD-L2) with by fastest (each panel reused 32x from L2).
// Race audit: buffer b is re-targeted exactly one full barrier interval after
// its last ds_read; each wave waits its OWN 4 staged loads (vmcnt counts only
// async16 ops - no other VMEM in the loop); numerics bit-identical.
__device__ __forceinline__ void gemm_step(const u16* __restrict__ bA,
                                          const u16* __restrict__ bB,
                                          int aoff, int boff, int kcp,
                                          f32x4 (&acc)[4][4]) {
  f16x8 av[4], bv[4];
#pragma unroll
  for (int i = 0; i < 4; ++i)
    av[i] = *(const f16x8*)&bA[(aoff + i * 16) * 32 + kcp];
#pragma unroll
  for (int j = 0; j < 4; ++j)
    bv[j] = *(const f16x8*)&bB[(boff + j * 16) * 32 + kcp];
#pragma unroll
  for (int i = 0; i < 4; ++i)
#pragma unroll
    for (int j = 0; j < 4; ++j)
      acc[i][j] = __builtin_amdgcn_mfma_f32_16x16x32_f16(av[i], bv[j], acc[i][j], 0, 0, 0);
}

__global__ __launch_bounds__(256) void k_gemm(const u16* __restrict__ A,
                                              const u16* __restrict__ Bm,
                                              const float* __restrict__ b_enc,
                                              u16* __restrict__ Cf16,
                                              float* __restrict__ fzero) {
  __shared__ u16 lA[3][128 * 32];
  __shared__ u16 lB[3][128 * 32];
  const int tid = threadIdx.x;
  const int lane = tid & 63, wave = tid >> 6;
  const int wm = wave >> 1, wn = wave & 1;
  // XCD column-stripe: wg%8 -> XCD (observed round-robin; perf-only heuristic)
  const int wg = blockIdx.x;           // 0..4095
  const int xcd = wg & 7, slot = wg >> 3;  // slot 0..511
  const int bx = xcd * 16 + (slot >> 5);   // 0..127 (16 bx per XCD)
  const int by = slot & 31;                // by fastest -> B-panel L2 reuse

  const int kcs = (tid & 3) ^ ((tid >> 3) & 3);  // swizzled source chunk
  const u16* gA0 = A + (size_t)(by * 128 + (tid >> 2)) * F_ + kcs * 8;
  const u16* gB0 = Bm + (size_t)(bx * 128 + (tid >> 2)) * F_ + kcs * 8;

#define STAGE(b_, k0_)                                   \
  {                                                      \
    async16(gA0 + (k0_), &lA[b_][tid * 8]);              \
    async16(gA0 + 64 * F_ + (k0_), &lA[b_][tid * 8 + 2048]); \
    async16(gB0 + (k0_), &lB[b_][tid * 8]);              \
    async16(gB0 + 64 * F_ + (k0_), &lB[b_][tid * 8 + 2048]); \
  }
#define STEP_SYNC(n_)                                    \
  {                                                      \
    asm volatile("s_waitcnt vmcnt(" #n_ ")" ::: "memory"); \
    __builtin_amdgcn_sched_barrier(0);                   \
    __builtin_amdgcn_s_barrier();                        \
    __builtin_amdgcn_sched_barrier(0);                   \
  }

  f32x4 acc[4][4] = {};
  const int lm = lane & 15;
  const int kcp = (((lane >> 4) ^ ((lm >> 1) & 3))) * 8;  // swizzled read offset
  const int aoff = wm * 64 + lm, boff = wn * 64 + lm;

  // prologue: tiles 0,1 staged; tile 0 resident after wait
  STAGE(0, 0);
  STAGE(1, 32);
  STEP_SYNC(4);

  // steady state: 30 steps (s=0..29), staging tiles 2..31
  int kc = 64;
  for (int s3 = 0; s3 < 30; s3 += 3) {
    STAGE(2, kc); kc += 32;
    gemm_step(lA[0], lB[0], aoff, boff, kcp, acc);
    STEP_SYNC(4);
    STAGE(0, kc); kc += 32;
    gemm_step(lA[1], lB[1], aoff, boff, kcp, acc);
    STEP_SYNC(4);
    STAGE(1, kc); kc += 32;
    gemm_step(lA[2], lB[2], aoff, boff, kcp, acc);
    STEP_SYNC(4);
  }
  // tail: tiles 30 (buf0) and 31 (buf1); tile31's loads complete at vmcnt(0)
  gemm_step(lA[0], lB[0], aoff, boff, kcp, acc);
  STEP_SYNC(0);
  gemm_step(lA[1], lB[1], aoff, boff, kcp, acc);
#undef STAGE
#undef STEP_SYNC

  // zero-fill slice of f's first half: 4096 blocks x 32 KB = 128 MB
  {
    float* zp = fzero + (size_t)wg * 8192 + tid * 4;
    const f32x4 z4 = {0.f, 0.f, 0.f, 0.f};
#pragma unroll
    for (int k = 0; k < 8; ++k)
      __builtin_nontemporal_store(z4, (f32x4*)(zp + k * 1024));
  }

#pragma unroll
  for (int i = 0; i < 4; ++i) {
    int rowg = by * 128 + wm * 64 + i * 16 + (lane >> 4) * 4;
#pragma unroll
    for (int j = 0; j < 4; ++j) {
      int colg = bx * 128 + wn * 64 + j * 16 + lm;
      float be = b_enc[colg];
      u16* cp = Cf16 + (size_t)rowg * H_ + colg;
#pragma unroll
      for (int r = 0; r < 4; ++r)
        cp[(size_t)r * H_] = f2h(acc[i][j][r] + be);
    }
  }
}

// ---- K2: fused select + refine (unchanged from passing round) ----
__global__ __launch_bounds__(256) void k_selref(const u16* __restrict__ af16,
                                                const float* __restrict__ x,
                                                const float* __restrict__ b_dec,
                                                const float* __restrict__ Wenc,
                                                const float* __restrict__ b_enc,
                                                int* __restrict__ decIdx,
                                                float* __restrict__ decVal) {
  const int row = blockIdx.x, tid = threadIdx.x;
  const int lane = tid & 63, wave = tid >> 6;
  __shared__ union { u16 sa[H_]; float wbuf[4][2][F_]; } u;  // 32 KB, reused
  __shared__ float xs[F_];       // 4 KB
  __shared__ int hist[NBINS];    // 8 KB
  __shared__ int coarse[256];    // 1 KB
  __shared__ double vals[MAXC];  // 1.5 KB
  __shared__ float bes[MAXC];
  __shared__ int idxs[MAXC];
  __shared__ float s_sureCut, s_ambLo;
  __shared__ int s_sure, s_amb;

  for (int i = tid; i < NBINS; i += 256) hist[i] = 0;
  if (tid == 0) { s_sure = 0; s_amb = 0; idxs[0] = 0; }
  for (int k = tid; k < F_; k += 256)
    xs[k] = x[(size_t)row * F_ + k] - b_dec[k];
  __syncthreads();

  const u16* arow = af16 + (size_t)row * H_;
  for (int i = tid; i < H_ / 8; i += 256) {
    u16x8 v = *(const u16x8*)(arow + i * 8);
    *(u16x8*)(u.sa + i * 8) = v;
#pragma unroll
    for (int c = 0; c < 8; ++c) {
      float fv = h2f(v[c]);
      int b = (int)floorf((fv + 4.0f) * 256.0f);
      b = b < 0 ? 0 : (b > NBINS - 1 ? NBINS - 1 : b);
      atomicAdd(&hist[b], 1);
    }
  }
  __syncthreads();
  {
    int s = 0;
#pragma unroll
    for (int j = 0; j < 8; ++j) s += hist[tid * 8 + j];
    coarse[tid] = s;
  }
  __syncthreads();
  if (tid == 0) {
    int c = 0, ifound = 0;
    for (int t = 255; t >= 0; --t) {
      if (c + coarse[t] >= TOPK) {
        for (int b = t * 8 + 7; b >= t * 8; --b) {
          c += hist[b];
          if (c >= TOPK) { ifound = b; break; }
        }
        break;
      }
      c += coarse[t];
    }
    float binlo = (float)ifound * BINW - 4.0f;  // binlo <= v64 < binlo+BINW
    s_sureCut = binlo + BINW + TWOE;            // a >  this: surely in top-64
    s_ambLo = binlo - TWOE;                     // a <  this: surely out
  }
  __syncthreads();

  const float sc = s_sureCut, al = s_ambLo;
  int* dI = decIdx + row * TOPK;
  float* dV = decVal + row * TOPK;
  for (int i = tid; i < H_ / 8; i += 256) {
    u16x8 v = *(const u16x8*)(u.sa + i * 8);
#pragma unroll
    for (int c = 0; c < 8; ++c) {
      float fv = h2f(v[c]);
      if (fv > sc) {
        int p = atomicAdd(&s_sure, 1);
        if (p < TOPK) { dI[p] = i * 8 + c; dV[p] = fv > 0.f ? fv : 0.f; }
      } else if (fv >= al) {
        int p = atomicAdd(&s_amb, 1);
        if (p < MAXC) idxs[p] = i * 8 + c;
      }
    }
  }
  __syncthreads();
  const int S = s_sure < TOPK ? s_sure : TOPK;
  const int cnt = s_amb < MAXC ? s_amb : MAXC;
  for (int c = tid; c < cnt; c += 256) bes[c] = b_enc[idxs[c]];
  __syncthreads();  // sa reads done -> wbuf alias safe; bes/idxs visible

  // candidate-invariant x slice -> fp32 registers
  float xr[16];
#pragma unroll
  for (int ch = 0; ch < 4; ++ch)
#pragma unroll
    for (int j = 0; j < 4; ++j)
      xr[ch * 4 + j] = xs[ch * 256 + lane * 4 + j];

#define ISSUE_ROW(c_, b_)                                                  \
  {                                                                        \
    int cc_ = (c_) < cnt ? (c_) : 0;                                       \
    const float* src_ = Wenc + (size_t)idxs[cc_] * F_ + lane * 4;          \
    float* dst_ = &u.wbuf[wave][(b_)][lane * 4];                           \
    async16(src_ + 0, dst_ + 0);                                           \
    async16(src_ + 256, dst_ + 256);                                       \
    async16(src_ + 512, dst_ + 512);                                       \
    async16(src_ + 768, dst_ + 768);                                       \
  }

  const int nIter = (cnt - wave + 3) / 4;
  ISSUE_ROW(wave, 0);
  ISSUE_ROW(wave + 4, 1);

  for (int i = 0; i < nIter; ++i) {
    const int c = wave + i * 4;
    const int bsel = i & 1;
    asm volatile("s_waitcnt vmcnt(4)" ::: "memory");
    __builtin_amdgcn_sched_barrier(0);

    const float4* wr = (const float4*)u.wbuf[wave][bsel];
    double s = 0.0;
#pragma unroll
    for (int ch = 0; ch < 4; ++ch) {
      float4 wv = wr[ch * 64 + lane];
      s = fma((double)xr[ch * 4 + 0], (double)wv.x, s);
      s = fma((double)xr[ch * 4 + 1], (double)wv.y, s);
      s = fma((double)xr[ch * 4 + 2], (double)wv.z, s);
      s = fma((double)xr[ch * 4 + 3], (double)wv.w, s);
    }
    __builtin_amdgcn_sched_barrier(0);
    ISSUE_ROW(wave + (i + 2) * 4, bsel);

#pragma unroll
    for (int off = 32; off > 0; off >>= 1) s += __shfl_xor(s, off);
    if (lane == 0 && c < cnt) vals[c] = s + (double)bes[c];
  }
#undef ISSUE_ROW
  __syncthreads();

  // exact ranking among ambiguous; top (TOPK - S) win slots S..TOPK-1
  const int Kp = TOPK - S;
  for (int c = tid; c < cnt; c += 256) {
    const double v = vals[c];
    const int h = idxs[c];
    int rank = 0;
    for (int o = 0; o < cnt; ++o) {
      double vo = vals[o];
      rank += (vo > v) || (vo == v && idxs[o] < h);  // jax tie-break
    }
    if (rank < Kp) {
      float fv = v > 0.0 ? (float)v : 0.0f;
      dI[S + rank] = h;
      dV[S + rank] = fv;
    }
  }
}

// ---- K3: zero f second half + scatter f + sparse decode ----
__global__ __launch_bounds__(256) void k_decode(const int* __restrict__ decIdx,
                                               const float* __restrict__ decVal,
                                               const u16* __restrict__ WdecT,
                                               const float* __restrict__ b_dec,
                                               float* __restrict__ f,
                                               float* __restrict__ xhat) {
  const int row = blockIdx.x, tid = threadIdx.x;
  __shared__ int sIdx[TOPK];
  __shared__ float sVal[TOPK];
  if (tid < TOPK) {
    sIdx[tid] = decIdx[row * TOPK + tid] & (H_ - 1);  // mask: fault-proof
    sVal[tid] = decVal[row * TOPK + tid];
  }
  float* frow = f + (size_t)row * H_;
  if (row >= B_ / 2) {  // second half held af16; now dead -> zero it here
    const f32x4 z4 = {0.f, 0.f, 0.f, 0.f};
    for (int i = tid; i < H_ / 4; i += 256)
      __builtin_nontemporal_store(z4, (f32x4*)frow + i);
  }
  __syncthreads();  // drains vmcnt: zeros committed before scatter
  if (tid < TOPK) frow[sIdx[tid]] = sVal[tid];

  const int fb = tid * 4;
  float4 bd = *(const float4*)(b_dec + fb);
  float a0 = bd.x, a1 = bd.y, a2 = bd.z, a3 = bd.w;
#pragma unroll 8
  for (int j = 0; j < TOPK; ++j) {
    const float v = sVal[j];
    const ushort4 w = *(const ushort4*)(WdecT + (size_t)sIdx[j] * F_ + fb);
    a0 += v * bf2f(w.x); a1 += v * bf2f(w.y);
    a2 += v * bf2f(w.z); a3 += v * bf2f(w.w);
  }
  float4 o; o.x = a0; o.y = a1; o.z = a2; o.w = a3;
  *(float4*)(xhat + (size_t)row * F_ + fb) = o;
}

extern "C" void kernel_launch(void* const* d_in, const int* in_sizes, int n_in,
                              void* d_out, int out_size, void* d_ws, size_t ws_size,
                              hipStream_t stream) {
  const float* x    = (const float*)d_in[0];
  const float* Wenc = (const float*)d_in[1];
  const float* benc = (const float*)d_in[2];
  const float* Wdec = (const float*)d_in[3];
  const float* bdec = (const float*)d_in[4];

  float* out  = (float*)d_out;
  float* f    = out;                       // [4096][16384] fp32
  float* xhat = out + (size_t)B_ * H_;     // [4096][1024]
  // fp16 'a' lives in the upper half of the f region (fully consumed by
  // k_selref before k_decode zero-fills that half) — no ws growth.
  u16* af16 = (u16*)(f + (size_t)B_ * H_ / 2);  // 128 MB

  char* ws = (char*)d_ws;
  u16*  xbar    = (u16*)ws;                             // 8 MB (fp16)
  u16*  wencb   = (u16*)(ws + (size_t)(8)  * 1048576);  // 32 MB (fp16)
  u16*  wdecT   = (u16*)(ws + (size_t)(40) * 1048576);  // 32 MB (bf16)
  int*  decIdx  = (int*)(ws + (size_t)(76) * 1048576);  // 1 MB
  float* decVal = (float*)(ws + (size_t)(77) * 1048576);// 1 MB

  k_xbar<<<B_ * F_ / 1024, 256, 0, stream>>>(x, bdec, xbar);
  k_cast<<<H_ * F_ / 1024, 256, 0, stream>>>(Wenc, wencb);
  k_transpose<<<dim3(H_ / 32, F_ / 32), 256, 0, stream>>>(Wdec, wdecT);
  k_gemm<<<4096, 256, 0, stream>>>(xbar, wencb, benc, af16, f);
  k_selref<<<B_, 256, 0, stream>>>(af16, x, bdec, Wenc, benc, decIdx, decVal);
  k_decode<<<B_, 256, 0, stream>>>(decIdx, decVal, wdecT, bdec, f, xhat);
}

// Round 4
// 743.814 us; speedup vs baseline: 1.0839x; 1.0839x over previous
//
#include <hip/hip_runtime.h>
#include <cstdint>

#define B_ 4096
#define F_ 1024
#define H_ 16384
#define TOPK 64
#define MAXC 192
// 2E: twice the bound on |a_fp16_stored - a_ref|.
// fp16-GEMM error <= 0.0031 (bf16's proven 0.025 scaled by 2^-3) +
// fp16 storage rounding <= 0.002  => E=0.010 gives ~2x headroom.
#define TWOE 0.020f

typedef unsigned short u16;
typedef __attribute__((ext_vector_type(8))) _Float16 f16x8;
typedef __attribute__((ext_vector_type(8))) unsigned short u16x8;
typedef __attribute__((ext_vector_type(4))) float f32x4;

__device__ __forceinline__ u16 f2bf(float f) {
  union { float f; uint32_t u; } v; v.f = f;
  uint32_t u = v.u;
  uint32_t r = u + 0x7FFFu + ((u >> 16) & 1u);
  return (u16)(r >> 16);
}
__device__ __forceinline__ float bf2f(u16 h) {
  union { uint32_t u; float f; } v; v.u = ((uint32_t)h) << 16; return v.f;
}
__device__ __forceinline__ u16 f2h(float f) {
  union { _Float16 h; u16 u; } v; v.h = (_Float16)f; return v.u;
}
__device__ __forceinline__ float h2f(u16 h) {
  union { _Float16 h; u16 u; } v; v.u = h; return (float)v.h;
}
// packed pair of fp16: zero any negative half (key space: monotone for >=0)
__device__ __forceinline__ uint32_t key2(uint32_t v) {
  uint32_t s = (v >> 15) & 0x00010001u;
  return v & ~(s * 0xFFFFu);
}

__device__ __forceinline__ void async16(const void* g, void* l) {
  __builtin_amdgcn_global_load_lds(
      reinterpret_cast<const __attribute__((address_space(1))) uint32_t*>(
          reinterpret_cast<uintptr_t>(g)),
      reinterpret_cast<__attribute__((address_space(3))) uint32_t*>(
          reinterpret_cast<uintptr_t>(l)),
      16, 0, 0);
}

// ---- K0a: xbar = fp16(x - b_dec) ----
__global__ __launch_bounds__(256) void k_xbar(const float* __restrict__ x,
                                              const float* __restrict__ b_dec,
                                              u16* __restrict__ xbar) {
  int i = blockIdx.x * 256 + threadIdx.x;
  int base = i * 4;
  int col = base & (F_ - 1);
  float4 xv = *(const float4*)(x + base);
  float4 bv = *(const float4*)(b_dec + col);
  ushort4 o;
  o.x = f2h(xv.x - bv.x); o.y = f2h(xv.y - bv.y);
  o.z = f2h(xv.z - bv.z); o.w = f2h(xv.w - bv.w);
  *(ushort4*)(xbar + base) = o;
}

// ---- K0b: fp16 cast of W_enc ----
__global__ __launch_bounds__(256) void k_cast(const float* __restrict__ src,
                                              u16* __restrict__ dst) {
  size_t base = (size_t)(blockIdx.x * 256 + threadIdx.x) * 4;
  float4 v = *(const float4*)(src + base);
  ushort4 o; o.x = f2h(v.x); o.y = f2h(v.y); o.z = f2h(v.z); o.w = f2h(v.w);
  *(ushort4*)(dst + base) = o;
}

// ---- K0c: W_dec [F,H] fp32 -> W_decT [H,F] bf16 (decode path unchanged) ----
__global__ __launch_bounds__(256) void k_transpose(const float* __restrict__ Wdec,
                                                   u16* __restrict__ WdecT) {
  __shared__ float tile[32][33];
  int hb = blockIdx.x * 32, fb = blockIdx.y * 32;
  int tx = threadIdx.x & 31, ty = threadIdx.x >> 5;  // ty 0..7
#pragma unroll
  for (int i = 0; i < 32; i += 8)
    tile[ty + i][tx] = Wdec[(size_t)(fb + ty + i) * H_ + hb + tx];
  __syncthreads();
#pragma unroll
  for (int i = 0; i < 32; i += 8)
    WdecT[(size_t)(hb + ty + i) * F_ + fb + tx] = f2bf(tile[tx][ty + i]);
}

// ---- K1: fp16 MFMA GEMM (round-2 known-good structure, reverted).
// Ring-3/vmcnt graft + XCD stripe regressed (FETCH 131->502 MB, occ 31->20):
// the stripe blew A's per-XCD L2 working set; counted-vmcnt on this 2-barrier
// structure is a known-null (m131-m140). Compute is at the m97 ceiling.
__global__ __launch_bounds__(256) void k_gemm(const u16* __restrict__ A,
                                              const u16* __restrict__ Bm,
                                              const float* __restrict__ b_enc,
                                              u16* __restrict__ Cf16,
                                              float* __restrict__ fzero) {
  __shared__ u16 lA[128 * 32];
  __shared__ u16 lB[128 * 32];
  const int tid = threadIdx.x;
  const int lane = tid & 63, wave = tid >> 6;
  const int wm = wave >> 1, wn = wave & 1;
  const int bx = blockIdx.x, by = blockIdx.y;

  const int kcs = (tid & 3) ^ ((tid >> 3) & 3);  // swizzled source chunk
  const u16* gA0 = A + (size_t)(by * 128 + (tid >> 2)) * F_ + kcs * 8;
  const u16* gB0 = Bm + (size_t)(bx * 128 + (tid >> 2)) * F_ + kcs * 8;
  u16* lA0 = &lA[tid * 8];
  u16* lB0 = &lB[tid * 8];

  f32x4 acc[4][4] = {};
  const int lm = lane & 15;
  const int kcp = (((lane >> 4) ^ ((lm >> 1) & 3))) * 8;  // swizzled read offset

  for (int k0 = 0; k0 < F_; k0 += 32) {
    async16(gA0 + k0, lA0);
    async16(gA0 + 64 * F_ + k0, lA0 + 2048);
    async16(gB0 + k0, lB0);
    async16(gB0 + 64 * F_ + k0, lB0 + 2048);
    __syncthreads();
    f16x8 av[4], bv[4];
#pragma unroll
    for (int i = 0; i < 4; ++i)
      av[i] = *(const f16x8*)&lA[(wm * 64 + i * 16 + lm) * 32 + kcp];
#pragma unroll
    for (int j = 0; j < 4; ++j)
      bv[j] = *(const f16x8*)&lB[(wn * 64 + j * 16 + lm) * 32 + kcp];
#pragma unroll
    for (int i = 0; i < 4; ++i)
#pragma unroll
      for (int j = 0; j < 4; ++j)
        acc[i][j] = __builtin_amdgcn_mfma_f32_16x16x32_f16(av[i], bv[j], acc[i][j], 0, 0, 0);
    __syncthreads();
  }

  // zero-fill slice of f's first half: 4096 blocks x 32 KB = 128 MB
  {
    const int bid = by * gridDim.x + bx;  // 0..4095
    float* zp = fzero + (size_t)bid * 8192 + tid * 4;
    const f32x4 z4 = {0.f, 0.f, 0.f, 0.f};
#pragma unroll
    for (int k = 0; k < 8; ++k)
      __builtin_nontemporal_store(z4, (f32x4*)(zp + k * 1024));
  }

#pragma unroll
  for (int i = 0; i < 4; ++i) {
    int rowg = by * 128 + wm * 64 + i * 16 + (lane >> 4) * 4;
#pragma unroll
    for (int j = 0; j < 4; ++j) {
      int colg = bx * 128 + wn * 64 + j * 16 + lm;
      float be = b_enc[colg];
      u16* cp = Cf16 + (size_t)rowg * H_ + colg;
#pragma unroll
      for (int r = 0; r < 4; ++r)
        cp[(size_t)r * H_] = f2h(acc[i][j][r] + be);
    }
  }
}

// ---- K2: fused select + refine.
// NEW selection: the 2048-bin LDS histogram (16384 atomicAdds/block, hot-bin
// serialization ~ the kernel's dominant cost) is replaced by a register-
// resident binary search on fp16 BIT PATTERNS (monotone for >=0; negative
// halfs keyed to 0 -- relu zeroes them in the reference and the cutoff is
// ~1.5 >> 0). 15 iterations x {64 packed int compares/thread -> shuffle
// reduce -> 4-entry LDS combine}; zero atomics; exact stored v64 (no bin
// slack). sure/amb classification and the fp64 refine pipeline unchanged.
__global__ __launch_bounds__(256) void k_selref(const u16* __restrict__ af16,
                                                const float* __restrict__ x,
                                                const float* __restrict__ b_dec,
                                                const float* __restrict__ Wenc,
                                                const float* __restrict__ b_enc,
                                                int* __restrict__ decIdx,
                                                float* __restrict__ decVal) {
  const int row = blockIdx.x, tid = threadIdx.x;
  const int lane = tid & 63, wave = tid >> 6;
  __shared__ float wbuf[4][2][F_];  // 32 KB refine gather buffers
  __shared__ float xs[F_];          // 4 KB
  __shared__ double vals[MAXC];     // 1.5 KB
  __shared__ float bes[MAXC];
  __shared__ int idxs[MAXC];
  __shared__ int s_cnt4[4];
  __shared__ int s_sure, s_amb;

  if (tid == 0) { s_sure = 0; s_amb = 0; idxs[0] = 0; }
  for (int k = tid; k < F_; k += 256)
    xs[k] = x[(size_t)row * F_ + k] - b_dec[k];

  // row -> registers as sort keys (64 halfs = 32 packed u32 per thread)
  // element index of pr[j*4+w] halves: base=(tid+256j)*8+2w (lo), +1 (hi)
  uint32_t pr[32];
  {
    const uint4* arow16 = (const uint4*)(af16 + (size_t)row * H_);
#pragma unroll
    for (int j = 0; j < 8; ++j) {
      uint4 v = arow16[tid + 256 * j];
      pr[j * 4 + 0] = key2(v.x);
      pr[j * 4 + 1] = key2(v.y);
      pr[j * 4 + 2] = key2(v.z);
      pr[j * 4 + 3] = key2(v.w);
    }
  }

  // binary search largest t with count(key >= t) >= TOPK  ->  t = stored v64
  uint32_t lo = 0, hi = 0x7C00;  // count(>=0)=16384 >= 64 > count(>=inf)=0
  while (hi - lo > 1) {
    const uint32_t mid = (lo + hi) >> 1;
    int c = 0;
#pragma unroll
    for (int r = 0; r < 32; ++r) {
      c += ((pr[r] & 0xFFFFu) >= mid);
      c += ((pr[r] >> 16) >= mid);
    }
#pragma unroll
    for (int off = 32; off > 0; off >>= 1) c += __shfl_xor(c, off);
    if (lane == 0) s_cnt4[wave] = c;
    __syncthreads();
    const int tot = s_cnt4[0] + s_cnt4[1] + s_cnt4[2] + s_cnt4[3];
    if (tot >= TOPK) lo = mid; else hi = mid;
    __syncthreads();
  }
  const float v64f = h2f((u16)lo);
  const float sc = v64f + TWOE;  // stored >  sc: surely in top-64
  const float al = v64f - TWOE;  // stored <  al: surely out

  int* dI = decIdx + row * TOPK;
  float* dV = decVal + row * TOPK;
#pragma unroll
  for (int j = 0; j < 8; ++j) {
#pragma unroll
    for (int w = 0; w < 4; ++w) {
      const uint32_t v = pr[j * 4 + w];
      const int ib = (tid + 256 * j) * 8 + w * 2;
      const float f0 = h2f((u16)(v & 0xFFFFu));
      const float f1 = h2f((u16)(v >> 16));
      if (f0 > sc) {
        int p = atomicAdd(&s_sure, 1);
        if (p < TOPK) { dI[p] = ib; dV[p] = f0 > 0.f ? f0 : 0.f; }
      } else if (f0 >= al) {
        int p = atomicAdd(&s_amb, 1);
        if (p < MAXC) idxs[p] = ib;
      }
      if (f1 > sc) {
        int p = atomicAdd(&s_sure, 1);
        if (p < TOPK) { dI[p] = ib + 1; dV[p] = f1 > 0.f ? f1 : 0.f; }
      } else if (f1 >= al) {
        int p = atomicAdd(&s_amb, 1);
        if (p < MAXC) idxs[p] = ib + 1;
      }
    }
  }
  __syncthreads();
  const int S = s_sure < TOPK ? s_sure : TOPK;
  const int cnt = s_amb < MAXC ? s_amb : MAXC;
  for (int c = tid; c < cnt; c += 256) bes[c] = b_enc[idxs[c]];
  __syncthreads();

  // candidate-invariant x slice -> fp32 registers
  float xr[16];
#pragma unroll
  for (int ch = 0; ch < 4; ++ch)
#pragma unroll
    for (int j = 0; j < 4; ++j)
      xr[ch * 4 + j] = xs[ch * 256 + lane * 4 + j];

#define ISSUE_ROW(c_, b_)                                                  \
  {                                                                        \
    int cc_ = (c_) < cnt ? (c_) : 0;                                       \
    const float* src_ = Wenc + (size_t)idxs[cc_] * F_ + lane * 4;          \
    float* dst_ = &wbuf[wave][(b_)][lane * 4];                             \
    async16(src_ + 0, dst_ + 0);                                           \
    async16(src_ + 256, dst_ + 256);                                       \
    async16(src_ + 512, dst_ + 512);                                       \
    async16(src_ + 768, dst_ + 768);                                       \
  }

  const int nIter = (cnt - wave + 3) / 4;
  ISSUE_ROW(wave, 0);
  ISSUE_ROW(wave + 4, 1);

  for (int i = 0; i < nIter; ++i) {
    const int c = wave + i * 4;
    const int bsel = i & 1;
    asm volatile("s_waitcnt vmcnt(4)" ::: "memory");
    __builtin_amdgcn_sched_barrier(0);

    const float4* wr = (const float4*)wbuf[wave][bsel];
    double s = 0.0;
#pragma unroll
    for (int ch = 0; ch < 4; ++ch) {
      float4 wv = wr[ch * 64 + lane];
      s = fma((double)xr[ch * 4 + 0], (double)wv.x, s);
      s = fma((double)xr[ch * 4 + 1], (double)wv.y, s);
      s = fma((double)xr[ch * 4 + 2], (double)wv.z, s);
      s = fma((double)xr[ch * 4 + 3], (double)wv.w, s);
    }
    __builtin_amdgcn_sched_barrier(0);
    ISSUE_ROW(wave + (i + 2) * 4, bsel);

#pragma unroll
    for (int off = 32; off > 0; off >>= 1) s += __shfl_xor(s, off);
    if (lane == 0 && c < cnt) vals[c] = s + (double)bes[c];
  }
#undef ISSUE_ROW
  __syncthreads();

  // exact ranking among ambiguous; top (TOPK - S) win slots S..TOPK-1
  const int Kp = TOPK - S;
  for (int c = tid; c < cnt; c += 256) {
    const double v = vals[c];
    const int h = idxs[c];
    int rank = 0;
    for (int o = 0; o < cnt; ++o) {
      double vo = vals[o];
      rank += (vo > v) || (vo == v && idxs[o] < h);  // jax tie-break
    }
    if (rank < Kp) {
      float fv = v > 0.0 ? (float)v : 0.0f;
      dI[S + rank] = h;
      dV[S + rank] = fv;
    }
  }
}

// ---- K3: zero f second half + scatter f + sparse decode ----
__global__ __launch_bounds__(256) void k_decode(const int* __restrict__ decIdx,
                                               const float* __restrict__ decVal,
                                               const u16* __restrict__ WdecT,
                                               const float* __restrict__ b_dec,
                                               float* __restrict__ f,
                                               float* __restrict__ xhat) {
  const int row = blockIdx.x, tid = threadIdx.x;
  __shared__ int sIdx[TOPK];
  __shared__ float sVal[TOPK];
  if (tid < TOPK) {
    sIdx[tid] = decIdx[row * TOPK + tid] & (H_ - 1);  // mask: fault-proof
    sVal[tid] = decVal[row * TOPK + tid];
  }
  float* frow = f + (size_t)row * H_;
  if (row >= B_ / 2) {  // second half held af16; now dead -> zero it here
    const f32x4 z4 = {0.f, 0.f, 0.f, 0.f};
    for (int i = tid; i < H_ / 4; i += 256)
      __builtin_nontemporal_store(z4, (f32x4*)frow + i);
  }
  __syncthreads();  // drains vmcnt: zeros committed before scatter
  if (tid < TOPK) frow[sIdx[tid]] = sVal[tid];

  const int fb = tid * 4;
  float4 bd = *(const float4*)(b_dec + fb);
  float a0 = bd.x, a1 = bd.y, a2 = bd.z, a3 = bd.w;
#pragma unroll 8
  for (int j = 0; j < TOPK; ++j) {
    const float v = sVal[j];
    const ushort4 w = *(const ushort4*)(WdecT + (size_t)sIdx[j] * F_ + fb);
    a0 += v * bf2f(w.x); a1 += v * bf2f(w.y);
    a2 += v * bf2f(w.z); a3 += v * bf2f(w.w);
  }
  float4 o; o.x = a0; o.y = a1; o.z = a2; o.w = a3;
  *(float4*)(xhat + (size_t)row * F_ + fb) = o;
}

extern "C" void kernel_launch(void* const* d_in, const int* in_sizes, int n_in,
                              void* d_out, int out_size, void* d_ws, size_t ws_size,
                              hipStream_t stream) {
  const float* x    = (const float*)d_in[0];
  const float* Wenc = (const float*)d_in[1];
  const float* benc = (const float*)d_in[2];
  const float* Wdec = (const float*)d_in[3];
  const float* bdec = (const float*)d_in[4];

  float* out  = (float*)d_out;
  float* f    = out;                       // [4096][16384] fp32
  float* xhat = out + (size_t)B_ * H_;     // [4096][1024]
  // fp16 'a' lives in the upper half of the f region (fully consumed by
  // k_selref before k_decode zero-fills that half) — no ws growth.
  u16* af16 = (u16*)(f + (size_t)B_ * H_ / 2);  // 128 MB

  char* ws = (char*)d_ws;
  u16*  xbar    = (u16*)ws;                             // 8 MB (fp16)
  u16*  wencb   = (u16*)(ws + (size_t)(8)  * 1048576);  // 32 MB (fp16)
  u16*  wdecT   = (u16*)(ws + (size_t)(40) * 1048576);  // 32 MB (bf16)
  int*  decIdx  = (int*)(ws + (size_t)(76) * 1048576);  // 1 MB
  float* decVal = (float*)(ws + (size_t)(77) * 1048576);// 1 MB

  k_xbar<<<B_ * F_ / 1024, 256, 0, stream>>>(x, bdec, xbar);
  k_cast<<<H_ * F_ / 1024, 256, 0, stream>>>(Wenc, wencb);
  k_transpose<<<dim3(H_ / 32, F_ / 32), 256, 0, stream>>>(Wdec, wdecT);
  k_gemm<<<dim3(H_ / 128, B_ / 128), 256, 0, stream>>>(xbar, wencb, benc, af16, f);
  k_selref<<<B_, 256, 0, stream>>>(af16, x, bdec, Wenc, benc, decIdx, decVal);
  k_decode<<<B_, 256, 0, stream>>>(decIdx, decVal, wdecT, bdec, f, xhat);
}